// Round 6
// baseline (352.131 us; speedup 1.0000x reference)
//
#include <hip/hip_runtime.h>
#include <hip/hip_bf16.h>
#include <math.h>

#define B 8
#define IC 256
#define OC 256
#define SDIM 512
#define H 128
#define W 128
#define OH 64
#define OW 64
#define EPS 1e-8f
#define SQRT2 1.41421356237309504880f
#define SCALE 0.02083333395421505f   // 1/sqrt(256*9)

#define RS 16640        // xbp row stride in elems (65*256)
#define PLANE 1081600   // 65*65*256 elems per phase plane

typedef unsigned short u16;
typedef unsigned int u32;
typedef __attribute__((ext_vector_type(8))) short s16x8;
typedef __attribute__((ext_vector_type(4))) float f32x4;

__device__ __forceinline__ void gl_lds16(const void* g, void* l) {
    __builtin_amdgcn_global_load_lds((const __attribute__((address_space(1))) u32*)g,
                                     (__attribute__((address_space(3))) u32*)l, 16, 0, 0);
}

// ---------------- wsq[o,i] = sum_tap w^2 ; block 0 also zeroes the blurpack zero-pad src ----
__global__ void wsq_kernel(const float* __restrict__ w, float* __restrict__ wsq,
                           float* __restrict__ zbuf) {
    int i = blockIdx.x * 256 + threadIdx.x;
    const float* p = w + (size_t)i * 9;
    float sum = 0.f;
    for (int k = 0; k < 9; ++k) sum = fmaf(p[k], p[k], sum);
    wsq[i] = sum;
    if (blockIdx.x == 0 && threadIdx.x < 64) zbuf[threadIdx.x] = 0.f;
}

// ---------------- fused style + demod (one block per batch b); also zeroes ssq ------------
__global__ __launch_bounds__(256) void style_demod_kernel(const float* __restrict__ s,
                                                          const float* __restrict__ sw,
                                                          const float* __restrict__ sb,
                                                          const float* __restrict__ wsq,
                                                          float* __restrict__ style,
                                                          float* __restrict__ demod,
                                                          float* __restrict__ ssq) {
    __shared__ float st[256];
    const int b = blockIdx.x;
    const int tid = threadIdx.x;
    // style[b, tid]
    const float4* sv = (const float4*)(s + (size_t)b * SDIM);
    const float4* wv = (const float4*)(sw + (size_t)tid * SDIM);
    float sum = 0.f;
    #pragma unroll 4
    for (int k = 0; k < 128; ++k) {
        float4 a4 = sv[k], b4 = wv[k];
        sum = fmaf(a4.x, b4.x, fmaf(a4.y, b4.y, fmaf(a4.z, b4.z, fmaf(a4.w, b4.w, sum))));
    }
    float styv = sum + sb[tid];
    style[(b << 8) + tid] = styv;
    st[tid] = styv;
    ssq[(b << 8) + tid] = 0.f;
    __syncthreads();
    // demod[b, o=tid]
    const float4* wq = (const float4*)(wsq + (size_t)tid * 256);
    float acc = 0.f;
    #pragma unroll 4
    for (int k = 0; k < 64; ++k) {
        float4 q = wq[k];
        float s0 = st[4 * k], s1 = st[4 * k + 1], s2 = st[4 * k + 2], s3 = st[4 * k + 3];
        acc = fmaf(s0 * s0, q.x, fmaf(s1 * s1, q.y, fmaf(s2 * s2, q.z, fmaf(s3 * s3, q.w, acc))));
    }
    demod[(b << 8) + tid] = rsqrtf(SCALE * SCALE * acc + EPS);
}

// ---------------- fused blur + pack v7: 4-row strips, 5 blocks/CU, 3D grid --------------
// Grid (strip=x, icg=y, b=z): the 4 ic-groups whose 16B quarters share one 64B xbp
// line are 32 dispatch-ids apart -> same XCD (round-robin), temporally adjacent ->
// line assembles in that XCD's L2 and writes back once.
__global__ __launch_bounds__(256, 5) void blurpack_kernel(const float* __restrict__ x,
                                                          __hip_bfloat16* __restrict__ xbp,
                                                          float* __restrict__ ssq,
                                                          const float* __restrict__ zbuf) {
    __shared__ __align__(16) char smem[32768];   // 8 rows x 256 granules x 16B
    u16 (*pbuf)[2][2][544] = reinterpret_cast<u16(*)[2][2][544]>(smem); // alias (8704 B)
    const float* rawf = (const float*)smem;
    const int strip = blockIdx.x;          // 0..31 (4 full-res rows each)
    const int ic0 = blockIdx.y << 3;
    const int b = blockIdx.z;
    const int t = threadIdx.x;

    // ---- stage: LDS pos (k, t) holds global granule sigma(t) of row strip*4-2+k ----
    {
        int gidx = t ^ ((t >> 3) & 7);     // involution
        int sch = gidx >> 5, cg5 = gidx & 31;
        const float* xch = x + (((size_t)(b * 256 + ic0 + sch)) << 14) + (cg5 << 2);
        char* dst = smem + t * 16;
        #pragma unroll
        for (int k = 0; k < 8; ++k) {
            int gr = (strip << 2) - 2 + k;
            const void* src = (gr >= 0 && gr < H) ? (const void*)(xch + ((size_t)gr << 7))
                                                  : (const void*)zbuf;
            gl_lds16(src, dst + (k << 12));
        }
    }
    __syncthreads();

    const int hr = t >> 7;                 // row within pair (0..1)
    const int ch = (t >> 4) & 7;
    const int cg = t & 15;
    // swizzled granule position for this thread's column block (cols 8cg..8cg+7)
    const int i0 = (ch << 5) + (cg << 1);  // even
    const int p0 = i0 ^ ((i0 >> 3) & 7);
    const int p1 = p0 ^ 1;                 // holds i0+1
    float ssacc = 0.f;
    uint2 res0[2], res1[2];                // packed even/odd cols per pass

    #pragma unroll
    for (int pass = 0; pass < 2; ++pass) {
        const int br = (pass << 1) + hr;   // reads rows br..br+4 (max 7)

        float v[8];
        #pragma unroll
        for (int j = 0; j < 8; ++j) v[j] = 0.f;
        #pragma unroll
        for (int rr = 0; rr < 5; ++rr) {
            const float wv = (rr == 2) ? 6.f : ((rr & 1) ? 4.f : 1.f);
            const int rb = (br + rr) << 10;   // row base in floats
            float4 q0 = *(const float4*)(rawf + rb + (p0 << 2));
            float4 q1 = *(const float4*)(rawf + rb + (p1 << 2));
            v[0] = fmaf(wv, q0.x, v[0]); v[1] = fmaf(wv, q0.y, v[1]);
            v[2] = fmaf(wv, q0.z, v[2]); v[3] = fmaf(wv, q0.w, v[3]);
            v[4] = fmaf(wv, q1.x, v[4]); v[5] = fmaf(wv, q1.y, v[5]);
            v[6] = fmaf(wv, q1.z, v[6]); v[7] = fmaf(wv, q1.w, v[7]);
        }

        float vm2 = __shfl_up(v[6], 1, 64);
        float vm1 = __shfl_up(v[7], 1, 64);
        float vp1 = __shfl_down(v[0], 1, 64);
        float vp2 = __shfl_down(v[1], 1, 64);
        if (cg == 0)  { vm2 = 0.f; vm1 = 0.f; }
        if (cg == 15) { vp1 = 0.f; vp2 = 0.f; }
        float e[12];
        e[0] = vm2; e[1] = vm1;
        #pragma unroll
        for (int j = 0; j < 8; ++j) e[2 + j] = v[j];
        e[10] = vp1; e[11] = vp2;

        u16 hp[8];
        #pragma unroll
        for (int j = 0; j < 8; ++j) {
            float hv = fmaf(6.f, e[j + 2], fmaf(4.f, e[j + 1] + e[j + 3], e[j] + e[j + 4]))
                     * (1.0f / 256.0f);
            ssacc = fmaf(hv, hv, ssacc);
            __hip_bfloat16 hb = __float2bfloat16(hv);
            hp[j] = *(u16*)&hb;
        }
        u16 w0[4] = {hp[0], hp[2], hp[4], hp[6]};
        u16 w1[4] = {hp[1], hp[3], hp[5], hp[7]};
        res0[pass] = *(const uint2*)w0;
        res1[pass] = *(const uint2*)w1;
    }

    __syncthreads();   // all raw reads complete; safe to overwrite with pbuf alias

    #pragma unroll
    for (int pass = 0; pass < 2; ++pass) {
        *(uint2*)&pbuf[pass][hr][0][(ch << 6) + (cg << 2)] = res0[pass];
        *(uint2*)&pbuf[pass][hr][1][(ch << 6) + (cg << 2)] = res1[pass];
    }
    __syncthreads();

    {
        int fc = t & 127;
        int hr2 = t >> 7;
        int pw = fc & 1, pcol = fc >> 1;
        #pragma unroll
        for (int pass = 0; pass < 2; ++pass) {
            uint4 g;
            u16* gp = (u16*)&g;
            #pragma unroll
            for (int c2 = 0; c2 < 8; ++c2)
                gp[c2] = pbuf[pass][hr2][pw][(c2 << 6) + pcol];
            size_t off = (size_t)((b << 2) + (hr2 << 1) + pw) * PLANE
                       + (size_t)((strip << 1) + pass + 1) * RS
                       + (size_t)(pcol + 1) * 256 + ic0;
            *(uint4*)(xbp + off) = g;
        }
    }

    float sv2 = ssacc;
    sv2 += __shfl_down(sv2, 8, 16);
    sv2 += __shfl_down(sv2, 4, 16);
    sv2 += __shfl_down(sv2, 2, 16);
    sv2 += __shfl_down(sv2, 1, 16);
    if (cg == 0) atomicAdd(&ssq[(b << 8) + ic0 + ch], sv2);
}

// ---------------- wf + zeropad fused ----------------
__global__ void wf_kernel(const float* __restrict__ w,
                          const float* __restrict__ demod,
                          const float* __restrict__ ssq,
                          const float* __restrict__ style,
                          const float* __restrict__ g,
                          __hip_bfloat16* __restrict__ wf,
                          __hip_bfloat16* __restrict__ xbp) {
    int bo = blockIdx.x;               // b*256+o
    int b = bo >> 8, o = bo & 255;
    int ic = threadIdx.x;
    float fac = rsqrtf(ssq[(b << 8) + ic] * (1.0f / 16384.0f) + EPS)
              * g[ic] * style[(b << 8) + ic] * SCALE;
    float m = demod[bo] * fac;
    const float* wp = w + ((size_t)o * 256 + ic) * 9;
    __hip_bfloat16* dst = wf + (size_t)bo * 2304 + ic;
    #pragma unroll
    for (int t = 0; t < 9; ++t)
        dst[t * 256] = __float2bfloat16(wp[t] * m);

    // zeropad: blocks 0..31 each clear pad row0/col0 of one phase plane
    if (bo < 32) {
        int t = threadIdx.x;
        char* base = (char*)(xbp + (size_t)bo * PLANE);
        uint4 z = {0u, 0u, 0u, 0u};
        for (int k = 0; k < 9; ++k) {
            int c = t + (k << 8);
            if (c < 2080) *(uint4*)(base + (size_t)c * 16) = z;
        }
        for (int k = 0; k < 8; ++k) {
            int c = t + (k << 8);
            int r = 1 + (c >> 5);
            int off = (c & 31) << 3;
            *(uint4*)(base + ((size_t)r * RS + off) * 2) = z;
        }
    }
}

// ---------------- MFMA implicit-GEMM conv v3: A global(L2)->regs, B-only LDS ----------------
// LDS traffic halves vs v2 (96->48 KB/block/K-step); A rides the VMEM/L2 pipe in
// parallel. wf is L2/L3-resident (9.4 MB); waves 0/2 (1/3) read identical A lines
// back-to-back within a K-step -> L1-served second read. A-regs double-buffered
// (aE/aO), loop unrolled x2 so all reg indices are compile-time (rule #20).
__global__ __launch_bounds__(256, 2) void conv_kernel(const __hip_bfloat16* __restrict__ xbp,
                                                      const __hip_bfloat16* __restrict__ wf,
                                                      const float* __restrict__ bias,
                                                      float* __restrict__ out) {
    // B-only LDS: buf0 [0,16K), buf1 [16K,32K). Each: 128 n-rows x 64 k x 2B.
    __shared__ char lds[32768];
    const int t = threadIdx.x;
    const int o0 = blockIdx.x << 7;
    const int y  = blockIdx.y;        // n-tile (128 n = 2 oh rows)
    const int b  = blockIdx.z;
    const size_t bb = (size_t)b << 8;

    // B staging byte-offsets (slot s = t + 256*j): LDS row r pos m holds granule m^(r&7)
    u32 boffs[4];
    #pragma unroll
    for (int j = 0; j < 4; ++j) {
        int s = t + (j << 8);
        int r = s >> 3, m = s & 7;
        int g = m ^ (r & 7);
        boffs[j] = (u32)((((y << 1) + (r >> 6)) * RS) + ((r & 63) << 8) + (g << 3)) * 2;
    }

    const int lane = t & 63, wave = t >> 6;
    const int lr = lane & 15, quad = lane >> 4;
    const int mb = (wave & 1) << 6;
    const int nb = (wave >> 1) << 6;

    // per-lane A row pointers: row = o0+mb+i*16+lr (x4608 B), + quad granule base
    const char* gA[4];
    #pragma unroll
    for (int i = 0; i < 4; ++i)
        gA[i] = (const char*)(wf + (bb + o0 + mb + (i << 4) + lr) * 2304) + (quad << 4);

    f32x4 acc[4][4];
    #pragma unroll
    for (int i = 0; i < 4; ++i)
        #pragma unroll
        for (int j = 0; j < 4; ++j) acc[i][j] = (f32x4){0.f, 0.f, 0.f, 0.f};

    // K-step cc in [0,36): tap = cc>>2, ic-quarter = (cc&3)*64
    // A row byte offset for step cc:
    #define KOFF(cc) ((((cc) >> 2) * 256 + (((cc) & 3) << 6)) * 2)

    #define LOAD_A(cc, arr)                                                                \
    {   const int ko_ = KOFF(cc);                                                          \
        _Pragma("unroll")                                                                  \
        for (int s_ = 0; s_ < 2; ++s_)                                                     \
            _Pragma("unroll")                                                              \
            for (int i_ = 0; i_ < 4; ++i_)                                                 \
                arr[s_ * 4 + i_] = *(const s16x8*)(gA[i_] + ko_ + (s_ << 6));              \
    }

    #define STAGE_B(cc, bufbase)                                                           \
    {                                                                                      \
        int tap = (cc) >> 2;                                                               \
        int icq = ((cc) & 3) << 6;                                                         \
        int th = (tap * 11) >> 5;                                                          \
        int tw = tap - th * 3;                                                             \
        int ph  = (th == 1) ? 0 : 1;                                                       \
        int dhp = (th == 0) ? 0 : 1;                                                       \
        int pw  = (tw == 1) ? 0 : 1;                                                       \
        int dwp = (tw == 0) ? 0 : 1;                                                       \
        const char* gB = (const char*)(xbp + (size_t)((b << 2) + (ph << 1) + pw) * PLANE   \
                                       + (size_t)dhp * RS + (dwp << 8) + icq);             \
        char* dB = (bufbase) + t * 16;                                                     \
        _Pragma("unroll")                                                                  \
        for (int j = 0; j < 4; ++j) gl_lds16(gB + boffs[j], dB + (j << 12));               \
    }

    #define COMPUTE(arr, bufbase)                                                          \
    {                                                                                      \
        _Pragma("unroll")                                                                  \
        for (int s_ = 0; s_ < 2; ++s_) {                                                   \
            const int mq_ = ((s_ << 2) + quad) ^ (lr & 7);                                 \
            s16x8 bf_[4];                                                                  \
            _Pragma("unroll")                                                              \
            for (int j_ = 0; j_ < 4; ++j_)                                                 \
                bf_[j_] = *(const s16x8*)((bufbase) + ((nb + (j_ << 4) + lr) << 7)         \
                                          + (mq_ << 4));                                   \
            _Pragma("unroll")                                                              \
            for (int i_ = 0; i_ < 4; ++i_)                                                 \
                _Pragma("unroll")                                                          \
                for (int j_ = 0; j_ < 4; ++j_)                                             \
                    acc[i_][j_] = __builtin_amdgcn_mfma_f32_16x16x32_bf16(                 \
                        arr[s_ * 4 + i_], bf_[j_], acc[i_][j_], 0, 0, 0);                  \
        }                                                                                  \
    }

    s16x8 aE[8], aO[8];
    LOAD_A(0, aE);
    STAGE_B(0, lds);
    __syncthreads();

    int cur = 0;
    for (int cc = 0; cc < 36; cc += 2) {
        // even step: prefetch step cc+1 (B->LDS other buf, A->aO), compute cc with aE
        STAGE_B(cc + 1, lds + ((cur ^ 1) << 14));
        LOAD_A(cc + 1, aO);
        COMPUTE(aE, lds + (cur << 14));
        __syncthreads();                  // drains vmcnt(0): B(cc+1) resident, aO loaded
        cur ^= 1;
        // odd step: prefetch step cc+2, compute cc+1 with aO
        if (cc + 2 < 36) {
            STAGE_B(cc + 2, lds + ((cur ^ 1) << 14));
            LOAD_A(cc + 2, aE);
        }
        COMPUTE(aO, lds + (cur << 14));
        __syncthreads();
        cur ^= 1;
    }
    #undef KOFF
    #undef LOAD_A
    #undef STAGE_B
    #undef COMPUTE

    // epilogue: bias + scaled LeakyReLU
    float bi[4][4];
    #pragma unroll
    for (int i = 0; i < 4; ++i)
        #pragma unroll
        for (int rr = 0; rr < 4; ++rr)
            bi[i][rr] = bias[o0 + mb + (i << 4) + (quad << 2) + rr];
    const int n0 = y << 7;
    #pragma unroll
    for (int i = 0; i < 4; ++i) {
        #pragma unroll
        for (int j = 0; j < 4; ++j) {
            #pragma unroll
            for (int rr = 0; rr < 4; ++rr) {
                int oc = o0 + mb + (i << 4) + (quad << 2) + rr;
                int n = n0 + nb + (j << 4) + lr;
                int oh = n >> 6, ow2 = n & 63;
                float v = acc[i][j][rr] + bi[i][rr];
                v = (v >= 0.f ? v : 0.2f * v) * SQRT2;
                out[((bb + oc) << 12) + (oh << 6) + ow2] = v;
            }
        }
    }
}

extern "C" void kernel_launch(void* const* d_in, const int* in_sizes, int n_in,
                              void* d_out, int out_size, void* d_ws, size_t ws_size,
                              hipStream_t stream) {
    const float* x   = (const float*)d_in[0];
    const float* s   = (const float*)d_in[1];
    const float* cw  = (const float*)d_in[2];
    const float* cb  = (const float*)d_in[3];
    const float* sw  = (const float*)d_in[4];
    const float* sb  = (const float*)d_in[5];
    const float* ng  = (const float*)d_in[6];
    float* out = (float*)d_out;

    char* ws = (char*)d_ws;
    __hip_bfloat16* xbp = (__hip_bfloat16*)ws;                   // 69,222,400 B
    __hip_bfloat16* wfb = (__hip_bfloat16*)(ws + 69222400);      //  9,437,184 B
    float* style  = (float*)(ws + 78659584);
    float* wsq    = style + 2048;
    float* demod  = wsq + 65536;
    float* ssq    = demod + 2048;
    float* zbuf   = ssq + 2048;        // 256 B of zeros (16B-aligned), halo source

    wsq_kernel<<<256, 256, 0, stream>>>(cw, wsq, zbuf);
    style_demod_kernel<<<8, 256, 0, stream>>>(s, sw, sb, wsq, style, demod, ssq);
    blurpack_kernel<<<dim3(32, 32, 8), 256, 0, stream>>>(x, xbp, ssq, zbuf);
    wf_kernel<<<2048, 256, 0, stream>>>(cw, demod, ssq, style, ng, wfb, xbp);
    conv_kernel<<<dim3(2, 32, 8), 256, 0, stream>>>(xbp, wfb, cb, out);
}

// Round 7
// 306.912 us; speedup vs baseline: 1.1473x; 1.1473x over previous
//
#include <hip/hip_runtime.h>
#include <hip/hip_bf16.h>
#include <math.h>

#define B 8
#define IC 256
#define OC 256
#define SDIM 512
#define H 128
#define W 128
#define OH 64
#define OW 64
#define EPS 1e-8f
#define SQRT2 1.41421356237309504880f
#define SCALE 0.02083333395421505f   // 1/sqrt(256*9)

#define RS 16640        // xbp row stride in elems (65*256)
#define PLANE 1081600   // 65*65*256 elems per phase plane

typedef unsigned short u16;
typedef unsigned int u32;
typedef __attribute__((ext_vector_type(8))) short s16x8;
typedef __attribute__((ext_vector_type(4))) float f32x4;

__device__ __forceinline__ void gl_lds16(const void* g, void* l) {
    __builtin_amdgcn_global_load_lds((const __attribute__((address_space(1))) u32*)g,
                                     (__attribute__((address_space(3))) u32*)l, 16, 0, 0);
}

// ---------------- wsq[o,i] = sum_tap w^2 ; block 0 also zeroes the blurpack zero-pad src ----
__global__ void wsq_kernel(const float* __restrict__ w, float* __restrict__ wsq,
                           float* __restrict__ zbuf) {
    int i = blockIdx.x * 256 + threadIdx.x;
    const float* p = w + (size_t)i * 9;
    float sum = 0.f;
    for (int k = 0; k < 9; ++k) sum = fmaf(p[k], p[k], sum);
    wsq[i] = sum;
    if (blockIdx.x == 0 && threadIdx.x < 64) zbuf[threadIdx.x] = 0.f;
}

// ---------------- fused style + demod (one block per batch b); also zeroes ssq ------------
__global__ __launch_bounds__(256) void style_demod_kernel(const float* __restrict__ s,
                                                          const float* __restrict__ sw,
                                                          const float* __restrict__ sb,
                                                          const float* __restrict__ wsq,
                                                          float* __restrict__ style,
                                                          float* __restrict__ demod,
                                                          float* __restrict__ ssq) {
    __shared__ float st[256];
    const int b = blockIdx.x;
    const int tid = threadIdx.x;
    // style[b, tid]
    const float4* sv = (const float4*)(s + (size_t)b * SDIM);
    const float4* wv = (const float4*)(sw + (size_t)tid * SDIM);
    float sum = 0.f;
    #pragma unroll 4
    for (int k = 0; k < 128; ++k) {
        float4 a4 = sv[k], b4 = wv[k];
        sum = fmaf(a4.x, b4.x, fmaf(a4.y, b4.y, fmaf(a4.z, b4.z, fmaf(a4.w, b4.w, sum))));
    }
    float styv = sum + sb[tid];
    style[(b << 8) + tid] = styv;
    st[tid] = styv;
    ssq[(b << 8) + tid] = 0.f;
    __syncthreads();
    // demod[b, o=tid]
    const float4* wq = (const float4*)(wsq + (size_t)tid * 256);
    float acc = 0.f;
    #pragma unroll 4
    for (int k = 0; k < 64; ++k) {
        float4 q = wq[k];
        float s0 = st[4 * k], s1 = st[4 * k + 1], s2 = st[4 * k + 2], s3 = st[4 * k + 3];
        acc = fmaf(s0 * s0, q.x, fmaf(s1 * s1, q.y, fmaf(s2 * s2, q.z, fmaf(s3 * s3, q.w, acc))));
    }
    demod[(b << 8) + tid] = rsqrtf(SCALE * SCALE * acc + EPS);
}

// ---------------- fused blur + pack v7: 4-row strips, 5 blocks/CU, 3D grid --------------
// Grid (strip=x, icg=y, b=z): the 4 ic-groups whose 16B quarters share one 64B xbp
// line are 32 dispatch-ids apart -> same XCD (round-robin), temporally adjacent ->
// line assembles in that XCD's L2 and writes back once.
__global__ __launch_bounds__(256, 5) void blurpack_kernel(const float* __restrict__ x,
                                                          __hip_bfloat16* __restrict__ xbp,
                                                          float* __restrict__ ssq,
                                                          const float* __restrict__ zbuf) {
    __shared__ __align__(16) char smem[32768];   // 8 rows x 256 granules x 16B
    u16 (*pbuf)[2][2][544] = reinterpret_cast<u16(*)[2][2][544]>(smem); // alias (8704 B)
    const float* rawf = (const float*)smem;
    const int strip = blockIdx.x;          // 0..31 (4 full-res rows each)
    const int ic0 = blockIdx.y << 3;
    const int b = blockIdx.z;
    const int t = threadIdx.x;

    // ---- stage: LDS pos (k, t) holds global granule sigma(t) of row strip*4-2+k ----
    {
        int gidx = t ^ ((t >> 3) & 7);     // involution
        int sch = gidx >> 5, cg5 = gidx & 31;
        const float* xch = x + (((size_t)(b * 256 + ic0 + sch)) << 14) + (cg5 << 2);
        char* dst = smem + t * 16;
        #pragma unroll
        for (int k = 0; k < 8; ++k) {
            int gr = (strip << 2) - 2 + k;
            const void* src = (gr >= 0 && gr < H) ? (const void*)(xch + ((size_t)gr << 7))
                                                  : (const void*)zbuf;
            gl_lds16(src, dst + (k << 12));
        }
    }
    __syncthreads();

    const int hr = t >> 7;                 // row within pair (0..1)
    const int ch = (t >> 4) & 7;
    const int cg = t & 15;
    // swizzled granule position for this thread's column block (cols 8cg..8cg+7)
    const int i0 = (ch << 5) + (cg << 1);  // even
    const int p0 = i0 ^ ((i0 >> 3) & 7);
    const int p1 = p0 ^ 1;                 // holds i0+1
    float ssacc = 0.f;
    uint2 res0[2], res1[2];                // packed even/odd cols per pass

    #pragma unroll
    for (int pass = 0; pass < 2; ++pass) {
        const int br = (pass << 1) + hr;   // reads rows br..br+4 (max 7)

        float v[8];
        #pragma unroll
        for (int j = 0; j < 8; ++j) v[j] = 0.f;
        #pragma unroll
        for (int rr = 0; rr < 5; ++rr) {
            const float wv = (rr == 2) ? 6.f : ((rr & 1) ? 4.f : 1.f);
            const int rb = (br + rr) << 10;   // row base in floats
            float4 q0 = *(const float4*)(rawf + rb + (p0 << 2));
            float4 q1 = *(const float4*)(rawf + rb + (p1 << 2));
            v[0] = fmaf(wv, q0.x, v[0]); v[1] = fmaf(wv, q0.y, v[1]);
            v[2] = fmaf(wv, q0.z, v[2]); v[3] = fmaf(wv, q0.w, v[3]);
            v[4] = fmaf(wv, q1.x, v[4]); v[5] = fmaf(wv, q1.y, v[5]);
            v[6] = fmaf(wv, q1.z, v[6]); v[7] = fmaf(wv, q1.w, v[7]);
        }

        float vm2 = __shfl_up(v[6], 1, 64);
        float vm1 = __shfl_up(v[7], 1, 64);
        float vp1 = __shfl_down(v[0], 1, 64);
        float vp2 = __shfl_down(v[1], 1, 64);
        if (cg == 0)  { vm2 = 0.f; vm1 = 0.f; }
        if (cg == 15) { vp1 = 0.f; vp2 = 0.f; }
        float e[12];
        e[0] = vm2; e[1] = vm1;
        #pragma unroll
        for (int j = 0; j < 8; ++j) e[2 + j] = v[j];
        e[10] = vp1; e[11] = vp2;

        u16 hp[8];
        #pragma unroll
        for (int j = 0; j < 8; ++j) {
            float hv = fmaf(6.f, e[j + 2], fmaf(4.f, e[j + 1] + e[j + 3], e[j] + e[j + 4]))
                     * (1.0f / 256.0f);
            ssacc = fmaf(hv, hv, ssacc);
            __hip_bfloat16 hb = __float2bfloat16(hv);
            hp[j] = *(u16*)&hb;
        }
        u16 w0[4] = {hp[0], hp[2], hp[4], hp[6]};
        u16 w1[4] = {hp[1], hp[3], hp[5], hp[7]};
        res0[pass] = *(const uint2*)w0;
        res1[pass] = *(const uint2*)w1;
    }

    __syncthreads();   // all raw reads complete; safe to overwrite with pbuf alias

    #pragma unroll
    for (int pass = 0; pass < 2; ++pass) {
        *(uint2*)&pbuf[pass][hr][0][(ch << 6) + (cg << 2)] = res0[pass];
        *(uint2*)&pbuf[pass][hr][1][(ch << 6) + (cg << 2)] = res1[pass];
    }
    __syncthreads();

    {
        int fc = t & 127;
        int hr2 = t >> 7;
        int pw = fc & 1, pcol = fc >> 1;
        #pragma unroll
        for (int pass = 0; pass < 2; ++pass) {
            uint4 g;
            u16* gp = (u16*)&g;
            #pragma unroll
            for (int c2 = 0; c2 < 8; ++c2)
                gp[c2] = pbuf[pass][hr2][pw][(c2 << 6) + pcol];
            size_t off = (size_t)((b << 2) + (hr2 << 1) + pw) * PLANE
                       + (size_t)((strip << 1) + pass + 1) * RS
                       + (size_t)(pcol + 1) * 256 + ic0;
            *(uint4*)(xbp + off) = g;
        }
    }

    float sv2 = ssacc;
    sv2 += __shfl_down(sv2, 8, 16);
    sv2 += __shfl_down(sv2, 4, 16);
    sv2 += __shfl_down(sv2, 2, 16);
    sv2 += __shfl_down(sv2, 1, 16);
    if (cg == 0) atomicAdd(&ssq[(b << 8) + ic0 + ch], sv2);
}

// ---------------- wf + zeropad fused ----------------
__global__ void wf_kernel(const float* __restrict__ w,
                          const float* __restrict__ demod,
                          const float* __restrict__ ssq,
                          const float* __restrict__ style,
                          const float* __restrict__ g,
                          __hip_bfloat16* __restrict__ wf,
                          __hip_bfloat16* __restrict__ xbp) {
    int bo = blockIdx.x;               // b*256+o
    int b = bo >> 8, o = bo & 255;
    int ic = threadIdx.x;
    float fac = rsqrtf(ssq[(b << 8) + ic] * (1.0f / 16384.0f) + EPS)
              * g[ic] * style[(b << 8) + ic] * SCALE;
    float m = demod[bo] * fac;
    const float* wp = w + ((size_t)o * 256 + ic) * 9;
    __hip_bfloat16* dst = wf + (size_t)bo * 2304 + ic;
    #pragma unroll
    for (int t = 0; t < 9; ++t)
        dst[t * 256] = __float2bfloat16(wp[t] * m);

    // zeropad: blocks 0..31 each clear pad row0/col0 of one phase plane
    if (bo < 32) {
        int t = threadIdx.x;
        char* base = (char*)(xbp + (size_t)bo * PLANE);
        uint4 z = {0u, 0u, 0u, 0u};
        for (int k = 0; k < 9; ++k) {
            int c = t + (k << 8);
            if (c < 2080) *(uint4*)(base + (size_t)c * 16) = z;
        }
        for (int k = 0; k < 8; ++k) {
            int c = t + (k << 8);
            int r = 1 + (c >> 5);
            int off = (c & 31) << 3;
            *(uint4*)(base + ((size_t)r * RS + off) * 2) = z;
        }
    }
}

// ---------------- MFMA implicit-GEMM conv v4: v2 structure + XCD-locality remap ----------
// A+B both staged via gl_lds into 64 KB double-buffered LDS (v2, round-5 best), but the
// flat 512-block grid is decoded so that all 32 y-blocks of one (o0,b) pair land on ONE
// XCD consecutively (bid%8 = XCD round-robin heuristic): the pair's 576 KB wf slice is
// fetched once and stays L2-resident (2 pairs/XCD = 1.15 MB < 4 MB), and adjacent-y
// xbp halo rows become L2-hits. R6 measured the cost of NOT doing this: FETCH 166 MB
// (~88 MB wf re-fetch), 2.1 TB/s, conv 96 us.
__global__ __launch_bounds__(256, 2) void conv_kernel(const __hip_bfloat16* __restrict__ xbp,
                                                      const __hip_bfloat16* __restrict__ wf,
                                                      const float* __restrict__ bias,
                                                      float* __restrict__ out) {
    // buffer layout: buf0 A [0,16K) B [16K,32K) ; buf1 A [32K,48K) B [48K,64K)
    // A-tile: 128 o-rows x 64 k x 2B (row stride 128B); B-tile: 128 n-rows x 64 k x 2B
    __shared__ char lds[65536];
    const int t = threadIdx.x;
    // bijective decode: bid = xcd + 8*(y + 32*half); pair p = xcd + 8*half
    const int bid = blockIdx.x;
    const int xcd = bid & 7;
    const int y   = (bid >> 3) & 31;       // n-tile (128 n = 2 oh rows)
    const int p   = xcd + (((bid >> 8) & 1) << 3);
    const int o0  = (p & 1) << 7;
    const int b   = p >> 1;
    const size_t bb = (size_t)b << 8;

    // staging byte-offsets for 4 A slots + 4 B slots (slot s = t + 256*j)
    // slot (row r, pos m): m in [0,8) granules of 16B; holds global granule g = m ^ (r&7)
    u32 aoffs[4], boffs[4];
    #pragma unroll
    for (int j = 0; j < 4; ++j) {
        int s = t + (j << 8);
        int r = s >> 3, m = s & 7;
        int g = m ^ (r & 7);
        aoffs[j] = (u32)(r * 2304 + (g << 3)) * 2;
        boffs[j] = (u32)((((y << 1) + (r >> 6)) * RS) + ((r & 63) << 8) + (g << 3)) * 2;
    }
    const char* gAbase = (const char*)(wf + (bb + o0) * 2304);

    const int lane = t & 63, wave = t >> 6;
    const int lr = lane & 15, quad = lane >> 4;
    const int mb = (wave & 1) << 6;
    const int nb = (wave >> 1) << 6;

    f32x4 acc[4][4];
    #pragma unroll
    for (int i = 0; i < 4; ++i)
        #pragma unroll
        for (int j = 0; j < 4; ++j) acc[i][j] = (f32x4){0.f, 0.f, 0.f, 0.f};

    // K-step c in [0,36): tap = c>>2, ic-quarter = (c&3)*64
    #define STAGE_TILE(cc, bufbase)                                                        \
    {                                                                                      \
        int tap = (cc) >> 2;                                                               \
        int icq = ((cc) & 3) << 6;                                                         \
        int th = (tap * 11) >> 5;                                                          \
        int tw = tap - th * 3;                                                             \
        int ph  = (th == 1) ? 0 : 1;                                                       \
        int dhp = (th == 0) ? 0 : 1;                                                       \
        int pw  = (tw == 1) ? 0 : 1;                                                       \
        int dwp = (tw == 0) ? 0 : 1;                                                       \
        const char* gA = gAbase + (size_t)(tap * 256 + icq) * 2;                           \
        const char* gB = (const char*)(xbp + (size_t)((b << 2) + (ph << 1) + pw) * PLANE   \
                                       + (size_t)dhp * RS + (dwp << 8) + icq);             \
        char* dA = (bufbase) + t * 16;                                                     \
        char* dB = (bufbase) + 16384 + t * 16;                                             \
        _Pragma("unroll")                                                                  \
        for (int j = 0; j < 4; ++j) gl_lds16(gA + aoffs[j], dA + (j << 12));               \
        _Pragma("unroll")                                                                  \
        for (int j = 0; j < 4; ++j) gl_lds16(gB + boffs[j], dB + (j << 12));               \
    }

    // prologue: stage tile 0 into buf0, drain, barrier
    STAGE_TILE(0, lds);
    __syncthreads();

    int cur = 0;
    for (int c = 0; c < 36; ++c) {
        // issue next tile's loads FIRST (into the other buffer) — they stay in
        // flight across the MFMA phase and are drained by the __syncthreads below
        if (c < 35) STAGE_TILE(c + 1, lds + ((cur ^ 1) << 15));

        const char* ldsA = lds + (cur << 15);
        const char* ldsB = ldsA + 16384;
        #pragma unroll
        for (int s = 0; s < 2; ++s) {
            const int mq = ((s << 2) + quad) ^ (lr & 7);
            s16x8 a[4], bf[4];
            #pragma unroll
            for (int i = 0; i < 4; ++i)
                a[i] = *(const s16x8*)(ldsA + ((mb + (i << 4) + lr) << 7) + (mq << 4));
            #pragma unroll
            for (int j = 0; j < 4; ++j)
                bf[j] = *(const s16x8*)(ldsB + ((nb + (j << 4) + lr) << 7) + (mq << 4));
            #pragma unroll
            for (int i = 0; i < 4; ++i)
                #pragma unroll
                for (int j = 0; j < 4; ++j)
                    acc[i][j] = __builtin_amdgcn_mfma_f32_16x16x32_bf16(a[i], bf[j], acc[i][j], 0, 0, 0);
        }
        __syncthreads();   // drains vmcnt(0): next tile resident; cur^1 safe to reuse
        cur ^= 1;
    }
    #undef STAGE_TILE

    // epilogue: bias + scaled LeakyReLU
    float bi[4][4];
    #pragma unroll
    for (int i = 0; i < 4; ++i)
        #pragma unroll
        for (int rr = 0; rr < 4; ++rr)
            bi[i][rr] = bias[o0 + mb + (i << 4) + (quad << 2) + rr];
    const int n0 = y << 7;
    #pragma unroll
    for (int i = 0; i < 4; ++i) {
        #pragma unroll
        for (int j = 0; j < 4; ++j) {
            #pragma unroll
            for (int rr = 0; rr < 4; ++rr) {
                int oc = o0 + mb + (i << 4) + (quad << 2) + rr;
                int n = n0 + nb + (j << 4) + lr;
                int oh = n >> 6, ow2 = n & 63;
                float v = acc[i][j][rr] + bi[i][rr];
                v = (v >= 0.f ? v : 0.2f * v) * SQRT2;
                out[((bb + oc) << 12) + (oh << 6) + ow2] = v;
            }
        }
    }
}

extern "C" void kernel_launch(void* const* d_in, const int* in_sizes, int n_in,
                              void* d_out, int out_size, void* d_ws, size_t ws_size,
                              hipStream_t stream) {
    const float* x   = (const float*)d_in[0];
    const float* s   = (const float*)d_in[1];
    const float* cw  = (const float*)d_in[2];
    const float* cb  = (const float*)d_in[3];
    const float* sw  = (const float*)d_in[4];
    const float* sb  = (const float*)d_in[5];
    const float* ng  = (const float*)d_in[6];
    float* out = (float*)d_out;

    char* ws = (char*)d_ws;
    __hip_bfloat16* xbp = (__hip_bfloat16*)ws;                   // 69,222,400 B
    __hip_bfloat16* wfb = (__hip_bfloat16*)(ws + 69222400);      //  9,437,184 B
    float* style  = (float*)(ws + 78659584);
    float* wsq    = style + 2048;
    float* demod  = wsq + 65536;
    float* ssq    = demod + 2048;
    float* zbuf   = ssq + 2048;        // 256 B of zeros (16B-aligned), halo source

    wsq_kernel<<<256, 256, 0, stream>>>(cw, wsq, zbuf);
    style_demod_kernel<<<8, 256, 0, stream>>>(s, sw, sb, wsq, style, demod, ssq);
    blurpack_kernel<<<dim3(32, 32, 8), 256, 0, stream>>>(x, xbp, ssq, zbuf);
    wf_kernel<<<2048, 256, 0, stream>>>(cw, demod, ssq, style, ng, wfb, xbp);
    conv_kernel<<<512, 256, 0, stream>>>(xbp, wfb, cb, out);
}